// Round 8
// baseline (253.591 us; speedup 1.0000x reference)
//
#include <hip/hip_runtime.h>

// SuperONN1d = implicit GEMM, split pipeline.
//   Stage 1 (xq_prep v5, unchanged): shift-lerp + powers -> XQ_T[b][lp][qc]
//     bf16. 64 l/block, reg-staged coalesced loads, 1 barrier, direct stores.
//   Stage 2 (prep_weights v8): wa rearranged so each wave's MFMA A-fragment
//     is a CONTIGUOUS 1024 B block (uniform base + lane*16) -> A is loaded
//     straight from global into registers with perfectly-coalesced
//     global_load_dwordx4, no LDS staging at all.
//   Stage 3 (gemm v8): round-7 counters showed the LDS read pipe at ~92 us
//     of the 111 us kernel (13,824 b128-reads/CU x 16 cyc incl 4-way phase
//     conflicts) -- the wall was LDS, not barriers. A now bypasses LDS:
//     LDS holds only the per-s B slice (17.4 KB), read traffic halves to
//     ~46 us, and the tap loop runs BARRIER-FREE (B is tap-invariant);
//     12 barriers/block instead of 108. A streams from L2 (864 KB resident,
//     1.77 GB total ~ 21 us of L2 pipe), latency hidden by 16 waves/CU.
//   LESSONS: (r4) scattered per-lane A gathers = 32 lines/inst, 2x slower --
//   fixed here by baking the fragment layout into wa so loads are contiguous.
//   (r3) occupancy > pipeline depth. (r6) don't serialize prep into the GEMM.

#define B_    16
#define CIN   128
#define L_    8192
#define COUT  128
#define K_    9
#define QMAX  3
#define KQ    (QMAX * CIN)        // 384
#define KTOT  (K_ * KQ)           // 3456
#define BK    64
#define GUARD 4
#define LROWS (L_ + 2 * GUARD)    // 8200
#define XQOFF (1u << 20)          // XQ at d_ws + 1 MB (A fragments first)
#define XSTR  73                  // xtile stride: odd -> conflict-free

typedef __attribute__((ext_vector_type(8)))  short bf16x8;
typedef __attribute__((ext_vector_type(16))) float f32x16;
typedef __attribute__((ext_vector_type(4)))  int   int4v;

__device__ __forceinline__ unsigned short f2bf(float v) {
    union { float f; unsigned u; } cv; cv.f = v;
    unsigned u = cv.u;
    return (unsigned short)((u + 0x7FFFu + ((u >> 16) & 1u)) >> 16);  // RNE
}

// ---- A prep v8: w[co][qc][tap] -> wave-fragment-contiguous layout.
//   1024B block id blk = ((c*2 + f)*2 + fi)*4 + kc; within: lane*16B + i*2B.
//   Element held by (lane, i) of fragment (c, f, fi, kc):
//     co = f*64 + fi*32 + (lane&31), k = c*64 + kc*16 + (lane>>5)*8 + i.
__global__ __launch_bounds__(256) void prep_weights(
    const float* __restrict__ w, unsigned short* __restrict__ wa)
{
    int g = blockIdx.x * 256 + threadIdx.x;
    if (g >= COUT * KTOT) return;
    const int blk    = g >> 9;           // 512 shorts = 1024 B per block
    const int within = g & 511;
    const int lane   = within >> 3;
    const int i      = within & 7;
    const int kc     = blk & 3;
    const int fi     = (blk >> 2) & 1;
    const int f      = (blk >> 3) & 1;
    const int c      = blk >> 4;
    const int co     = f * 64 + fi * 32 + (lane & 31);
    const int k      = c * 64 + kc * 16 + (lane >> 5) * 8 + i;
    const int tap    = k / KQ;
    const int qc     = k - tap * KQ;
    wa[g] = f2bf(w[((size_t)co * KQ + qc) * K_ + tap]);
}

// ---- XQ prep v5 (unchanged): 64 l/block, reg-staged, direct stores ----
__global__ __launch_bounds__(256) void xq_prep(
    const float* __restrict__ x, const float* __restrict__ shifts,
    unsigned short* __restrict__ xq)
{
    __shared__ float xtile[128 * XSTR];          // 37,376 B -> 4 blocks/CU
    const int l0   = blockIdx.x * 64;
    const int b    = blockIdx.y;
    const int tid  = threadIdx.x;
    const int lane = tid & 63;
    const int w4   = tid >> 6;
    const float* xb = x + (size_t)b * CIN * L_;

    float rv[32], rn[4];
    const int gcol = l0 - 4 + lane;
    const bool cok = (gcol >= 0) & (gcol < L_);
#pragma unroll
    for (int j = 0; j < 32; ++j) {
        const int r = w4 * 32 + j;
        rv[j] = cok ? xb[(size_t)r * L_ + gcol] : 0.0f;
    }
    const int ncol = l0 + 60 + (tid & 7);
    const bool nok = ncol < L_;
#pragma unroll
    for (int it = 0; it < 4; ++it) {
        const int r = it * 32 + (tid >> 3);
        rn[it] = nok ? xb[(size_t)r * L_ + ncol] : 0.0f;
    }
#pragma unroll
    for (int j = 0; j < 32; ++j)
        xtile[(w4 * 32 + j) * XSTR + lane] = rv[j];
#pragma unroll
    for (int it = 0; it < 4; ++it)
        xtile[(it * 32 + (tid >> 3)) * XSTR + 64 + (tid & 7)] = rn[it];
    __syncthreads();

    {
        const int ci    = tid & 127;
        const int lhalf = tid >> 7;
        const float sh = shifts[2 * ci] * 4.0f;  // MAX_SHIFT
        const float fl = floorf(sh);
        const int  ifl = (int)fl;
        const float w1 = sh - fl;
        int c0 = lhalf * 32 + 4 + ifl;
        unsigned short* orow =
            xq + ((size_t)b * LROWS + l0 + GUARD + lhalf * 32) * KQ + ci;
        float v_prev = xtile[ci * XSTR + c0];
#pragma unroll
        for (int j = 0; j < 32; ++j) {
            const float v_next = xtile[ci * XSTR + c0 + 1];
            const float xs = fmaf(w1, v_next - v_prev, v_prev);
            const float x2 = xs * xs;
            const float x3 = x2 * xs;
            orow[0]   = f2bf(xs);
            orow[128] = f2bf(x2);
            orow[256] = f2bf(x3);
            v_prev = v_next;
            ++c0;
            orow += KQ;
        }
    }

    if (blockIdx.x == 0) {          // zero guard rows lp 0..3
        int4v* g0 = (int4v*)(xq + (size_t)b * LROWS * KQ);
        if (tid < 192) g0[tid] = (int4v){0, 0, 0, 0};
    }
    if (blockIdx.x == gridDim.x - 1) {  // zero guard rows lp 8196..8199
        int4v* g1 = (int4v*)(xq + ((size_t)b * LROWS + L_ + GUARD) * KQ);
        if (tid < 192) g1[tid] = (int4v){0, 0, 0, 0};
    }
}

// ---- GEMM v8: A global->regs (coalesced frags), B in LDS, barrier-free taps ----
__global__ __launch_bounds__(256, 4) void gemm(
    const unsigned short* __restrict__ wa,   // fragment-contiguous bf16
    const unsigned short* __restrict__ xq,   // [B_][LROWS][KQ] bf16
    const float*          __restrict__ bias,
    float*                __restrict__ out)
{
    __shared__ __align__(16) unsigned short ldsB[136 * BK];   // 17,408 B

    const int l0   = blockIdx.x * 128;
    const int b    = blockIdx.y;
    const int tid  = threadIdx.x;
    const int lane = tid & 63;
    const int w    = tid >> 6;               // 0..3
    const int f      = w >> 1;               // co half
    const int cobase = f * 64;
    const int nbase  = (w & 1) * 64;
    const int n5 = lane & 31;
    const int h  = lane >> 5;

    // B DMA lane pattern: lane j -> row (j>>3), slot (j&7)^((j>>3)&7)
    const int bj_row = lane >> 3;
    const size_t bLaneOff = (size_t)bj_row * KQ + (size_t)(((lane & 7) ^ (bj_row & 7)) << 3);

    f32x16 acc[2][2];
#pragma unroll
    for (int i = 0; i < 2; ++i)
#pragma unroll
        for (int j = 0; j < 2; ++j) acc[i][j] = (f32x16){};

    const unsigned short* xqb   = xq + (size_t)b * LROWS * KQ;
    const unsigned short* bbase = xqb + (size_t)l0 * KQ + bLaneOff;
    // A fragment base for this wave: + c*8192 + (fi*4+kc)*512 shorts
    const unsigned short* abase = wa + ((size_t)f << 12) + (size_t)lane * 8;

#pragma unroll 1
    for (int s = 0; s < 6; ++s) {
        // stage B column slice s: rows l0..l0+135, cols s*64..s*64+63
        const unsigned short* bsrc = bbase + s * 64;
#pragma unroll
        for (int i = 0; i < 4; ++i) {
            const int g = w * 4 + i;
            __builtin_amdgcn_global_load_lds(
                (const __attribute__((address_space(1))) void*)(bsrc + (size_t)g * 8 * KQ),
                (__attribute__((address_space(3))) void*)((char*)ldsB + g * 1024),
                16, 0, 0);
        }
        if (w == 0)
            __builtin_amdgcn_global_load_lds(
                (const __attribute__((address_space(1))) void*)(bsrc + (size_t)16 * 8 * KQ),
                (__attribute__((address_space(3))) void*)((char*)ldsB + 16 * 1024),
                16, 0, 0);
        __syncthreads();   // B slice resident (drains A loads too - fine)

        // ---- barrier-free tap loop: A from global (L2-hot, coalesced) ----
#pragma unroll 1
        for (int tap = 0; tap < K_; ++tap) {
            const int c = tap * 6 + s;
            const unsigned short* ab = abase + ((size_t)c << 13);  // c*8192
            bf16x8 A[2][4];
#pragma unroll
            for (int fi = 0; fi < 2; ++fi)
#pragma unroll
                for (int kc = 0; kc < 4; ++kc)
                    A[fi][kc] = *(const bf16x8*)(ab + (size_t)((fi << 2) | kc) * 512);
#pragma unroll
            for (int kc = 0; kc < 4; ++kc) {
                const int br0 = tap + nbase + n5;
                const int ba0 = br0 * 128 + ((((kc << 1) | h) ^ (br0 & 7)) << 4);
                const int ba1 = ba0 + 32 * 128;   // (br0+32)&7 == br0&7
                const bf16x8 b0 = *(const bf16x8*)((const char*)ldsB + ba0);
                const bf16x8 b1 = *(const bf16x8*)((const char*)ldsB + ba1);
                acc[0][0] = __builtin_amdgcn_mfma_f32_32x32x16_bf16(A[0][kc], b0, acc[0][0], 0, 0, 0);
                acc[0][1] = __builtin_amdgcn_mfma_f32_32x32x16_bf16(A[0][kc], b1, acc[0][1], 0, 0, 0);
                acc[1][0] = __builtin_amdgcn_mfma_f32_32x32x16_bf16(A[1][kc], b0, acc[1][0], 0, 0, 0);
                acc[1][1] = __builtin_amdgcn_mfma_f32_32x32x16_bf16(A[1][kc], b1, acc[1][1], 0, 0, 0);
            }
        }
        __syncthreads();   // all B reads done before next s's DMA overwrites
    }

    // ---- epilogue: + bias, coalesced stores ----
#pragma unroll
    for (int fi = 0; fi < 2; ++fi)
#pragma unroll
        for (int bj = 0; bj < 2; ++bj)
#pragma unroll
            for (int r = 0; r < 16; ++r) {
                const int co = cobase + fi * 32 + (r & 3) + 8 * (r >> 2) + 4 * h;
                const int l  = l0 + nbase + bj * 32 + n5;
                out[((size_t)(b * COUT + co)) * L_ + l] = acc[fi][bj][r] + bias[co];
            }
}

extern "C" void kernel_launch(void* const* d_in, const int* in_sizes, int n_in,
                              void* d_out, int out_size, void* d_ws, size_t ws_size,
                              hipStream_t stream) {
    const float* x      = (const float*)d_in[0];  // 16*128*8192
    const float* w      = (const float*)d_in[1];  // 128*384*9
    const float* bias   = (const float*)d_in[2];  // 128
    const float* shifts = (const float*)d_in[3];  // 128*2
    float* out = (float*)d_out;

    const size_t need = (size_t)XQOFF + (size_t)B_ * LROWS * KQ * 2;  // ~101.8 MB
    if (ws_size < need) return;   // clean fail instead of OOB corruption

    unsigned short* wa = (unsigned short*)d_ws;                       // 884,736 B
    unsigned short* xq = (unsigned short*)((char*)d_ws + XQOFF);      // 100.76 MB

    const int nw = COUT * KTOT;                                       // 442,368
    prep_weights<<<(nw + 255) / 256, 256, 0, stream>>>(w, wa);

    dim3 gq(L_ / 64, B_);                                             // 128 x 16 = 2048
    xq_prep<<<gq, 256, 0, stream>>>(x, shifts, xq);

    dim3 gg(L_ / 128, B_);                                            // 64 x 16 = 1024
    gemm<<<gg, 256, 0, stream>>>(wa, xq, bias, out);
}

// Round 9
// 239.261 us; speedup vs baseline: 1.0599x; 1.0599x over previous
//
#include <hip/hip_runtime.h>

// SuperONN1d = implicit GEMM, split pipeline.
//   Stage 1 (xq_prep v5, unchanged): shift-lerp + powers -> XQ_T[b][lp][qc].
//   Stage 2 (prep_weights): r7 swizzled per-chunk layout (identity DMA ->
//     conflict-free LDS A tile). r8's fragment-contiguous layout reverted.
//   Stage 3 (gemm v9): acc[2][4] deep tile. Block 128co x 256l, 4 waves
//     (wave = 64co x 128l), 512 blocks = exactly 2 resident/CU.
//     Read ratio drops 1.0 -> 0.75 b128/MFMA (per kc: 2 A + 4 B reads feed
//     8 MFMAs) -> LDS pipe ~52 us ~ MFMA 46.5 us (was 69 vs 46.5).
//     A double-buffered (32 KB) + counted s_waitcnt vmcnt(4) + raw barriers:
//     next chunk's DMA stays in flight across compute, no vmcnt(0) drains
//     inside the tap loop (2 blocks/CU can't hide drains like r7's 4 could).
//   LESSONS: (r4,r8) A via global->reg = exposed L2 latency/gathers, 2x
//   slower -- A stays on DMA->LDS. (r3) pipeline without a read-ratio cut
//   pays occupancy for nothing. (r6) don't serialize prep into the GEMM.
//   (r7/r8 counters) ~4 cyc/b128 "conflict" is intrinsic (m134: b128=12cyc),
//   not a swizzle bug -- cut read COUNT, not conflict rate.

#define B_    16
#define CIN   128
#define L_    8192
#define COUT  128
#define K_    9
#define QMAX  3
#define KQ    (QMAX * CIN)        // 384
#define KTOT  (K_ * KQ)           // 3456
#define BK    64
#define GUARD 4
#define LROWS (L_ + 2 * GUARD)    // 8200
#define XQOFF (1u << 20)          // XQ at d_ws + 1 MB (A fragments first)
#define XSTR  73                  // xtile stride: odd -> conflict-free
#define BROWS 264                 // B slice rows: 256 l + 8 tap halo

typedef __attribute__((ext_vector_type(8)))  short bf16x8;
typedef __attribute__((ext_vector_type(16))) float f32x16;
typedef __attribute__((ext_vector_type(4)))  int   int4v;

__device__ __forceinline__ unsigned short f2bf(float v) {
    union { float f; unsigned u; } cv; cv.f = v;
    unsigned u = cv.u;
    return (unsigned short)((u + 0x7FFFu + ((u >> 16) & 1u)) >> 16);  // RNE
}

// ---- A prep (r7): w[co][qc][tap] -> wa[c][co][slot s8][i], swizzled:
//   LDS 16B-slot (co, s8) must hold elements k = c*64 + (s8 ^ (co&7))*8 + i
__global__ __launch_bounds__(256) void prep_weights(
    const float* __restrict__ w, unsigned short* __restrict__ wa)
{
    int g = blockIdx.x * 256 + threadIdx.x;
    if (g >= COUT * KTOT) return;
    const int c   = g >> 13;             // chunk (8192 shorts each)
    const int r   = g & 8191;
    const int co  = r >> 6;              // row = 64 shorts = 128 B
    const int s8  = (r >> 3) & 7;
    const int i   = r & 7;
    const int kk  = ((s8 ^ (co & 7)) << 3) | i;
    const int k   = c * BK + kk;
    const int tap = k / KQ;
    const int qc  = k - tap * KQ;
    wa[g] = f2bf(w[((size_t)co * KQ + qc) * K_ + tap]);
}

// ---- XQ prep v5 (unchanged): 64 l/block, reg-staged, direct stores ----
__global__ __launch_bounds__(256) void xq_prep(
    const float* __restrict__ x, const float* __restrict__ shifts,
    unsigned short* __restrict__ xq)
{
    __shared__ float xtile[128 * XSTR];          // 37,376 B -> 4 blocks/CU
    const int l0   = blockIdx.x * 64;
    const int b    = blockIdx.y;
    const int tid  = threadIdx.x;
    const int lane = tid & 63;
    const int w4   = tid >> 6;
    const float* xb = x + (size_t)b * CIN * L_;

    float rv[32], rn[4];
    const int gcol = l0 - 4 + lane;
    const bool cok = (gcol >= 0) & (gcol < L_);
#pragma unroll
    for (int j = 0; j < 32; ++j) {
        const int r = w4 * 32 + j;
        rv[j] = cok ? xb[(size_t)r * L_ + gcol] : 0.0f;
    }
    const int ncol = l0 + 60 + (tid & 7);
    const bool nok = ncol < L_;
#pragma unroll
    for (int it = 0; it < 4; ++it) {
        const int r = it * 32 + (tid >> 3);
        rn[it] = nok ? xb[(size_t)r * L_ + ncol] : 0.0f;
    }
#pragma unroll
    for (int j = 0; j < 32; ++j)
        xtile[(w4 * 32 + j) * XSTR + lane] = rv[j];
#pragma unroll
    for (int it = 0; it < 4; ++it)
        xtile[(it * 32 + (tid >> 3)) * XSTR + 64 + (tid & 7)] = rn[it];
    __syncthreads();

    {
        const int ci    = tid & 127;
        const int lhalf = tid >> 7;
        const float sh = shifts[2 * ci] * 4.0f;  // MAX_SHIFT
        const float fl = floorf(sh);
        const int  ifl = (int)fl;
        const float w1 = sh - fl;
        int c0 = lhalf * 32 + 4 + ifl;
        unsigned short* orow =
            xq + ((size_t)b * LROWS + l0 + GUARD + lhalf * 32) * KQ + ci;
        float v_prev = xtile[ci * XSTR + c0];
#pragma unroll
        for (int j = 0; j < 32; ++j) {
            const float v_next = xtile[ci * XSTR + c0 + 1];
            const float xs = fmaf(w1, v_next - v_prev, v_prev);
            const float x2 = xs * xs;
            const float x3 = x2 * xs;
            orow[0]   = f2bf(xs);
            orow[128] = f2bf(x2);
            orow[256] = f2bf(x3);
            v_prev = v_next;
            ++c0;
            orow += KQ;
        }
    }

    if (blockIdx.x == 0) {          // zero guard rows lp 0..3
        int4v* g0 = (int4v*)(xq + (size_t)b * LROWS * KQ);
        if (tid < 192) g0[tid] = (int4v){0, 0, 0, 0};
    }
    if (blockIdx.x == gridDim.x - 1) {  // zero guard rows lp 8196..8199
        int4v* g1 = (int4v*)(xq + ((size_t)b * LROWS + L_ + GUARD) * KQ);
        if (tid < 192) g1[tid] = (int4v){0, 0, 0, 0};
    }
}

// ---- GEMM v9: 128x256 tile, acc[2][4], A dbuf + counted vmcnt ----
__global__ __launch_bounds__(256, 2) void gemm(
    const unsigned short* __restrict__ wa,   // [54][128][64] swizzled bf16
    const unsigned short* __restrict__ xq,   // [B_][LROWS][KQ] bf16
    const float*          __restrict__ bias,
    float*                __restrict__ out)
{
    __shared__ __align__(16) unsigned short ldsA[2][COUT * BK];  // 32 KB
    __shared__ __align__(16) unsigned short ldsB[BROWS * BK];    // 33,792 B

    const int l0   = blockIdx.x * 256;
    const int b    = blockIdx.y;
    const int tid  = threadIdx.x;
    const int lane = tid & 63;
    const int w    = tid >> 6;               // 0..3
    const int cobase = (w >> 1) * 64;
    const int nbase  = (w & 1) * 128;
    const int n5 = lane & 31;
    const int h  = lane >> 5;

    // B DMA lane pattern: lane j -> row (j>>3), slot (j&7)^((j>>3)&7)
    const int bj_row = lane >> 3;
    const size_t bLaneOff = (size_t)bj_row * KQ + (size_t)(((lane & 7) ^ (bj_row & 7)) << 3);

    // loop-invariant A fragment LDS byte addresses (XOR-swizzled)
    int aaddr[2][4];
#pragma unroll
    for (int fi = 0; fi < 2; ++fi)
#pragma unroll
        for (int kc = 0; kc < 4; ++kc) {
            const int ar = cobase + fi * 32 + n5;
            aaddr[fi][kc] = ar * 128 + ((((kc << 1) | h) ^ (ar & 7)) << 4);
        }

    f32x16 acc[2][4];
#pragma unroll
    for (int i = 0; i < 2; ++i)
#pragma unroll
        for (int j = 0; j < 4; ++j) acc[i][j] = (f32x16){};

    const unsigned short* xqb   = xq + (size_t)b * LROWS * KQ;
    const unsigned short* bbase = xqb + (size_t)l0 * KQ + bLaneOff;
    const unsigned short* aw    = wa + (size_t)(w * 4) * 512 + (size_t)lane * 8;

    // B stage: 33 groups of 1024 B (rows 8g..8g+7)
#define STAGE_B(sv)                                                            \
    {                                                                          \
        const unsigned short* bsrc = bbase + (sv) * 64;                        \
        _Pragma("unroll")                                                      \
        for (int i = 0; i < 8; ++i) {                                          \
            const int g = w * 8 + i;                                           \
            __builtin_amdgcn_global_load_lds(                                  \
                (const __attribute__((address_space(1))) void*)(bsrc + (size_t)g * 8 * KQ), \
                (__attribute__((address_space(3))) void*)((char*)ldsB + g * 1024), \
                16, 0, 0);                                                     \
        }                                                                      \
        if (w == 0)                                                            \
            __builtin_amdgcn_global_load_lds(                                  \
                (const __attribute__((address_space(1))) void*)(bsrc + (size_t)32 * 8 * KQ), \
                (__attribute__((address_space(3))) void*)((char*)ldsB + 32 * 1024), \
                16, 0, 0);                                                     \
    }

#define LOAD_A(cv, buf)                                                        \
    {                                                                          \
        const unsigned short* agsrc = aw + (size_t)(cv) * 8192;                \
        char* adst = (char*)ldsA[buf];                                         \
        _Pragma("unroll")                                                      \
        for (int i = 0; i < 4; ++i)                                            \
            __builtin_amdgcn_global_load_lds(                                  \
                (const __attribute__((address_space(1))) void*)(agsrc + i * 512), \
                (__attribute__((address_space(3))) void*)(adst + (w * 4 + i) * 1024), \
                16, 0, 0);                                                     \
    }

    // prologue: B(0) + A chunk 0 -> buf0, full drain
    STAGE_B(0);
    LOAD_A(0, 0);
    __syncthreads();

    int par = 0;
#pragma unroll 1
    for (int s = 0; s < 6; ++s) {
#pragma unroll 1
        for (int tap = 0; tap < K_; ++tap) {
            if (tap < 8) {
                LOAD_A((tap + 1) * 6 + s, par ^ 1);
                asm volatile("s_waitcnt vmcnt(4)" ::: "memory");
            } else if (s < 5) {
                LOAD_A(s + 1, par ^ 1);          // tap0 chunk of next s
                asm volatile("s_waitcnt vmcnt(4)" ::: "memory");
            } else {
                asm volatile("s_waitcnt vmcnt(0)" ::: "memory");
            }
            __builtin_amdgcn_s_barrier();
            __builtin_amdgcn_sched_barrier(0);

            __builtin_amdgcn_s_setprio(1);
            const char* Ab = (const char*)ldsA[par];
#pragma unroll
            for (int kc = 0; kc < 4; ++kc) {
                const int br0 = tap + nbase + n5;
                const int ba0 = br0 * 128 + ((((kc << 1) | h) ^ (br0 & 7)) << 4);
                const bf16x8 a0 = *(const bf16x8*)(Ab + aaddr[0][kc]);
                const bf16x8 a1 = *(const bf16x8*)(Ab + aaddr[1][kc]);
#pragma unroll
                for (int bj = 0; bj < 4; ++bj) {
                    // (br0 + 32*bj)&7 == br0&7 -> same swizzle, +4096 B/frag
                    const bf16x8 bb = *(const bf16x8*)((const char*)ldsB + ba0 + bj * 4096);
                    acc[0][bj] = __builtin_amdgcn_mfma_f32_32x32x16_bf16(a0, bb, acc[0][bj], 0, 0, 0);
                    acc[1][bj] = __builtin_amdgcn_mfma_f32_32x32x16_bf16(a1, bb, acc[1][bj], 0, 0, 0);
                }
            }
            __builtin_amdgcn_s_setprio(0);
            __builtin_amdgcn_sched_barrier(0);
            __builtin_amdgcn_s_barrier();        // reads of buf[par] done
            __builtin_amdgcn_sched_barrier(0);
            par ^= 1;
        }
        if (s < 5) {                              // restage B for next s
            STAGE_B(s + 1);
            __syncthreads();                      // drains B (+A prefetch)
        }
    }

    // ---- epilogue: + bias, coalesced stores ----
#pragma unroll
    for (int fi = 0; fi < 2; ++fi)
#pragma unroll
        for (int bj = 0; bj < 4; ++bj)
#pragma unroll
            for (int r = 0; r < 16; ++r) {
                const int co = cobase + fi * 32 + (r & 3) + 8 * (r >> 2) + 4 * h;
                const int l  = l0 + nbase + bj * 32 + n5;
                out[((size_t)(b * COUT + co)) * L_ + l] = acc[fi][bj][r] + bias[co];
            }
#undef STAGE_B
#undef LOAD_A
}

extern "C" void kernel_launch(void* const* d_in, const int* in_sizes, int n_in,
                              void* d_out, int out_size, void* d_ws, size_t ws_size,
                              hipStream_t stream) {
    const float* x      = (const float*)d_in[0];  // 16*128*8192
    const float* w      = (const float*)d_in[1];  // 128*384*9
    const float* bias   = (const float*)d_in[2];  // 128
    const float* shifts = (const float*)d_in[3];  // 128*2
    float* out = (float*)d_out;

    const size_t need = (size_t)XQOFF + (size_t)B_ * LROWS * KQ * 2;  // ~101.8 MB
    if (ws_size < need) return;   // clean fail instead of OOB corruption

    unsigned short* wa = (unsigned short*)d_ws;                       // 884,736 B
    unsigned short* xq = (unsigned short*)((char*)d_ws + XQOFF);      // 100.76 MB

    const int nw = COUT * KTOT;                                       // 442,368
    prep_weights<<<(nw + 255) / 256, 256, 0, stream>>>(w, wa);

    dim3 gq(L_ / 64, B_);                                             // 128 x 16 = 2048
    xq_prep<<<gq, 256, 0, stream>>>(x, shifts, xq);

    dim3 gg(L_ / 256, B_);                                            // 32 x 16 = 512
    gemm<<<gg, 256, 0, stream>>>(wa, xq, bias, out);
}